// Round 1
// baseline (33840.430 us; speedup 1.0000x reference)
//
#include <hip/hip_runtime.h>
#include <hip/hip_bf16.h>

#define B_   2048
#define L_   128
#define V_   64
#define H_   501
#define KP_  512
#define T_   127
#define BT_  16
#define NWG_ 128
#define NTH_ 512

typedef __attribute__((ext_vector_type(8))) short short8;
typedef __attribute__((ext_vector_type(4))) float f32x4;

#define MFMA(acc, a, b) acc = __builtin_amdgcn_mfma_f32_16x16x32_bf16((a), (b), (acc), 0, 0, 0)

__device__ __forceinline__ float sigm(float x){ return 1.f/(1.f + __expf(-x)); }
__device__ __forceinline__ float tanh_(float x){ float e = __expf(2.f*x); return 1.f - 2.f/(e + 1.f); }
__device__ __forceinline__ unsigned short f2bf(float x){
  unsigned u = __float_as_uint(x);
  u += 0x7fffu + ((u >> 16) & 1u);
  return (unsigned short)(u >> 16);
}

// ---- prologue kernels ----

// dst[mtx][g][j][k] bf16, mtx order: whh0, wih1, whh1, wih2, whh2. src all [1503][501]
__global__ void k_pack_w(const float* w0,const float* w1,const float* w2,const float* w3,const float* w4,
                         unsigned short* dst){
  int idx = blockIdx.x*256 + threadIdx.x;
  if (idx >= 5*3*512*512) return;
  int k = idx & 511; int j = (idx>>9) & 511; int lg = idx>>18; int g = lg%3; int l = lg/3;
  const float* src = (l==0)?w0:(l==1)?w1:(l==2)?w2:(l==3)?w3:w4;
  float v = 0.f;
  if (j < H_ && k < H_) v = src[(size_t)(g*H_ + j)*H_ + k];
  dst[idx] = f2bf(v);
}

__global__ void k_pack_linw(const float* lw, unsigned short* dst){
  int idx = blockIdx.x*256 + threadIdx.x;
  if (idx >= 64*512) return;
  int k = idx & 511, v = idx >> 9;
  dst[idx] = f2bf((k < H_) ? lw[v*H_ + k] : 0.f);
}

// dst[bias][g][j]: order bhh0, bih1, bhh1, bih2, bhh2
__global__ void k_pack_bias(const float* b0,const float* b1,const float* b2,const float* b3,const float* b4,
                            float* dst){
  int idx = blockIdx.x*256 + threadIdx.x;
  if (idx >= 5*1536) return;
  int j = idx & 511; int g = (idx>>9)%3; int l = idx/1536;
  const float* s = (l==0)?b0:(l==1)?b1:(l==2)?b2:(l==3)?b3:b4;
  dst[idx] = (j < H_) ? s[g*H_ + j] : 0.f;
}

// EW[v][g][j] = sum_k emb[v][k] * wih0[g*501+j][k], k<128
__global__ void k_ew(const float* emb, const float* wih0, float* EW){
  int idx = blockIdx.x*256 + threadIdx.x;
  if (idx >= 64*1536) return;
  int j = idx & 511; int g = (idx>>9)%3; int v = idx/1536;
  float s = 0.f;
  if (j < H_){
    const float* wr = wih0 + (size_t)(g*H_ + j)*257;
    const float* e  = emb + v*128;
    for (int k=0;k<128;++k) s += e[k]*wr[k];
  }
  EW[idx] = s;
}

// Cb[b][g][j] = bih0[gj] + z[b,:] @ wih0[gj, 128:256] + y[b]*wih0[gj, 256]
__global__ void k_cb(const float* z, const float* y, const float* bih0, const float* wih0, float* Cb){
  int idx = blockIdx.x*256 + threadIdx.x;
  if (idx >= B_*1536) return;
  int j = idx & 511; int g = (idx>>9)%3; int b = idx/1536;
  float s = 0.f;
  if (j < H_){
    int row = g*H_ + j;
    const float* wr = wih0 + (size_t)row*257 + 128;
    const float* zr = z + b*128;
    s = bih0[row] + y[b]*wr[128];
    for (int k=0;k<128;++k) s += zr[k]*wr[k];
  }
  Cb[idx] = s;
}

__global__ void k_out0(float* out){
  int idx = blockIdx.x*256 + threadIdx.x;
  if (idx >= B_*64) return;
  int v = idx & 63, b = idx >> 6;
  out[(size_t)b*(L_*V_) + v] = (v==1) ? 1.f : 0.f;
}

// ---- main persistent GRU kernel ----

// A-fragment from swizzled bf16 LDS: row r (batch), k = s*32 + lrow*8 .. +8
__device__ __forceinline__ short8 lds_afrag(const unsigned short* hb, int r, int s, int lrow){
  int byte = (r<<10) + (s<<6) + (lrow<<4);
  byte ^= ((r&7)<<4);
  return *(const short8*)((const char*)hb + byte);
}

__global__ __launch_bounds__(NTH_, 2) void k_gru(
  const int* __restrict__ xin, const unsigned short* __restrict__ Wp,
  const unsigned short* __restrict__ LinW, const float* __restrict__ EW,
  const float* __restrict__ Cb, const float* __restrict__ biasP,
  const float* __restrict__ linb, float* __restrict__ out)
{
  __shared__ unsigned short hsh[3*16*512];   // 48 KB: h0,h1,h2 bf16, XOR-swizzled

  const int tid  = threadIdx.x;
  const int wid  = tid >> 6;
  const int lane = tid & 63;
  const int lrow = lane >> 4;      // k-chunk for A/B frags; row-group for C/D
  const int lcol = lane & 15;      // A row / B col / C col
  const int b0   = blockIdx.x * BT_;

  for (int i = tid; i < 3*16*512; i += NTH_) hsh[i] = 0;

  float hm[3][4][4];               // fp32 master copy of h for this thread's tiles
  #pragma unroll
  for (int l=0;l<3;++l)
    #pragma unroll
    for (int tt=0;tt<4;++tt)
      #pragma unroll
      for (int i=0;i<4;++i) hm[l][tt][i]=0.f;

  __syncthreads();

  #pragma unroll 1
  for (int t = 0; t < T_; ++t){
    int tok[4];
    #pragma unroll
    for (int i=0;i<4;++i){
      int m = lrow*4 + i;
      tok[i] = (t==0) ? 1 : xin[(b0+m)*L_ + t];
    }

    // ---------- layer 0: gh = h0 @ whh0^T ; gi from EW/Cb lookup ----------
    #pragma unroll
    for (int tt=0; tt<4; ++tt){
      const int j = (wid + 8*tt)*16 + lcol;
      f32x4 aR={0,0,0,0}, aZ={0,0,0,0}, aNH={0,0,0,0};
      const unsigned short* w_r = Wp + ((size_t)(0*3+0)*512 + j)*512;
      const unsigned short* w_z = Wp + ((size_t)(0*3+1)*512 + j)*512;
      const unsigned short* w_n = Wp + ((size_t)(0*3+2)*512 + j)*512;
      #pragma unroll 4
      for (int s=0; s<16; ++s){
        short8 a = lds_afrag(hsh, lcol, s, lrow);
        int ko = s*32 + lrow*8;
        MFMA(aR, a, *(const short8*)(w_r + ko));
        MFMA(aZ, a, *(const short8*)(w_z + ko));
        MFMA(aNH,a, *(const short8*)(w_n + ko));
      }
      float br = biasP[0*1536 +        j];
      float bz = biasP[0*1536 +  512 + j];
      float bn = biasP[0*1536 + 1024 + j];
      #pragma unroll
      for (int i=0;i<4;++i){
        int m = lrow*4 + i;
        const float* ewp = EW + tok[i]*1536;
        const float* cbp = Cb + (size_t)(b0+m)*1536;
        float ir  = ewp[j]        + cbp[j];
        float iz  = ewp[512+j]    + cbp[512+j];
        float inn = ewp[1024+j]   + cbp[1024+j];
        float r  = sigm(ir + aR[i] + br);
        float zg = sigm(iz + aZ[i] + bz);
        float n  = tanh_(inn + r*(aNH[i] + bn));
        float hnew = (1.f - zg)*n + zg*hm[0][tt][i];
        hm[0][tt][i] = (j < H_) ? hnew : 0.f;
      }
    }
    __syncthreads();
    #pragma unroll
    for (int tt=0; tt<4; ++tt){
      int j = (wid + 8*tt)*16 + lcol;
      if (j < H_){
        #pragma unroll
        for (int i=0;i<4;++i){
          int m = lrow*4 + i;
          int byte = (m<<10) + (j<<1); byte ^= ((m&7)<<4);
          *(unsigned short*)((char*)hsh + byte) = f2bf(hm[0][tt][i]);
        }
      }
    }
    __syncthreads();

    // ---------- layers 1, 2 ----------
    #pragma unroll
    for (int l = 1; l <= 2; ++l){
      const int mI = 1 + (l-1)*2;   // wih_l
      const int mH = 2 + (l-1)*2;   // whh_l
      #pragma unroll
      for (int tt=0; tt<4; ++tt){
        const int j = (wid + 8*tt)*16 + lcol;
        f32x4 aR={0,0,0,0}, aZ={0,0,0,0}, aNI={0,0,0,0}, aNH={0,0,0,0};
        const unsigned short* wi_r = Wp + ((size_t)(mI*3+0)*512 + j)*512;
        const unsigned short* wi_z = Wp + ((size_t)(mI*3+1)*512 + j)*512;
        const unsigned short* wi_n = Wp + ((size_t)(mI*3+2)*512 + j)*512;
        const unsigned short* wh_r = Wp + ((size_t)(mH*3+0)*512 + j)*512;
        const unsigned short* wh_z = Wp + ((size_t)(mH*3+1)*512 + j)*512;
        const unsigned short* wh_n = Wp + ((size_t)(mH*3+2)*512 + j)*512;
        #pragma unroll 4
        for (int s=0; s<16; ++s){
          short8 ap = lds_afrag(hsh + (l-1)*8192, lcol, s, lrow);
          short8 as = lds_afrag(hsh +  l   *8192, lcol, s, lrow);
          int ko = s*32 + lrow*8;
          MFMA(aR, ap, *(const short8*)(wi_r + ko));
          MFMA(aZ, ap, *(const short8*)(wi_z + ko));
          MFMA(aNI,ap, *(const short8*)(wi_n + ko));
          MFMA(aR, as, *(const short8*)(wh_r + ko));
          MFMA(aZ, as, *(const short8*)(wh_z + ko));
          MFMA(aNH,as, *(const short8*)(wh_n + ko));
        }
        const int bI = mI, bH = mH;
        float bir = biasP[bI*1536 +        j], bhr = biasP[bH*1536 +        j];
        float biz = biasP[bI*1536 +  512 + j], bhz = biasP[bH*1536 +  512 + j];
        float bin = biasP[bI*1536 + 1024 + j], bhn = biasP[bH*1536 + 1024 + j];
        #pragma unroll
        for (int i=0;i<4;++i){
          float r  = sigm(aR[i] + bir + bhr);
          float zg = sigm(aZ[i] + biz + bhz);
          float n  = tanh_(aNI[i] + bin + r*(aNH[i] + bhn));
          float hnew = (1.f - zg)*n + zg*hm[l][tt][i];
          hm[l][tt][i] = (j < H_) ? hnew : 0.f;
        }
      }
      __syncthreads();
      #pragma unroll
      for (int tt=0; tt<4; ++tt){
        int j = (wid + 8*tt)*16 + lcol;
        if (j < H_){
          #pragma unroll
          for (int i=0;i<4;++i){
            int m = lrow*4 + i;
            int byte = (m<<10) + (j<<1); byte ^= ((m&7)<<4);
            *(unsigned short*)((char*)hsh + l*16384 + byte) = f2bf(hm[l][tt][i]);
          }
        }
      }
      __syncthreads();
    }

    // ---------- logits: h2 @ lin_w^T + lin_b (waves 0-3) ----------
    if (wid < 4){
      const int j = wid*16 + lcol;       // vocab index
      f32x4 acc={0,0,0,0};
      const unsigned short* lw = LinW + (size_t)j*512;
      #pragma unroll 4
      for (int s=0; s<16; ++s){
        short8 a = lds_afrag(hsh + 2*8192, lcol, s, lrow);
        MFMA(acc, a, *(const short8*)(lw + s*32 + lrow*8));
      }
      float lb = linb[j];
      #pragma unroll
      for (int i=0;i<4;++i){
        int m = lrow*4 + i;
        out[(size_t)(b0+m)*(L_*V_) + (size_t)(t+1)*V_ + j] = acc[i] + lb;
      }
    }
  }
}

extern "C" void kernel_launch(void* const* d_in, const int* in_sizes, int n_in,
                              void* d_out, int out_size, void* d_ws, size_t ws_size,
                              hipStream_t stream)
{
  const float* z    = (const float*)d_in[0];
  const float* y    = (const float*)d_in[1];
  const int*   xin  = (const int*)d_in[2];
  const float* emb  = (const float*)d_in[3];
  const float* linw = (const float*)d_in[4];
  const float* linb = (const float*)d_in[5];
  const float* wih0 = (const float*)d_in[6];
  const float* whh0 = (const float*)d_in[7];
  const float* bih0 = (const float*)d_in[8];
  const float* bhh0 = (const float*)d_in[9];
  const float* wih1 = (const float*)d_in[10];
  const float* whh1 = (const float*)d_in[11];
  const float* bih1 = (const float*)d_in[12];
  const float* bhh1 = (const float*)d_in[13];
  const float* wih2 = (const float*)d_in[14];
  const float* whh2 = (const float*)d_in[15];
  const float* bih2 = (const float*)d_in[16];
  const float* bhh2 = (const float*)d_in[17];
  float* out = (float*)d_out;

  char* ws = (char*)d_ws;
  unsigned short* Wp   = (unsigned short*)(ws);                               // 7,864,320 B
  unsigned short* LinW = (unsigned short*)(ws + 7864320);                     //    65,536 B
  float* EW    = (float*)(ws + 7864320 + 65536);                              //   393,216 B
  float* Cb    = (float*)(ws + 7864320 + 65536 + 393216);                     // 12,582,912 B
  float* BiasP = (float*)(ws + 7864320 + 65536 + 393216 + 12582912);          //    30,720 B

  k_pack_w   <<<(5*3*512*512 + 255)/256, 256, 0, stream>>>(whh0, wih1, whh1, wih2, whh2, Wp);
  k_pack_linw<<<(64*512      + 255)/256, 256, 0, stream>>>(linw, LinW);
  k_pack_bias<<<(5*1536      + 255)/256, 256, 0, stream>>>(bhh0, bih1, bhh1, bih2, bhh2, BiasP);
  k_ew       <<<(64*1536     + 255)/256, 256, 0, stream>>>(emb, wih0, EW);
  k_cb       <<<(B_*1536     + 255)/256, 256, 0, stream>>>(z, y, bih0, wih0, Cb);
  k_out0     <<<(B_*64       + 255)/256, 256, 0, stream>>>(out);
  k_gru      <<<NWG_, NTH_, 0, stream>>>(xin, Wp, LinW, EW, Cb, BiasP, linb, out);
}